// Round 1
// baseline (1056.500 us; speedup 1.0000x reference)
//
#include <hip/hip_runtime.h>
#include <float.h>

// GenerativeUpsample BCE get_keep + prune.
// Inputs: fea (N,64) f32, pred_f (N,1) f32, batch_ids (N,) i32 sorted,
//         target_points_num (8,) i32.
// Outputs (concat): pruned_fea (N*64) f32, keep (N,) written as 0/1 f32.
//
// Plan: exact per-batch kth-smallest via 4-pass 8-bit MSD radix select on the
// monotonic uint transform of the float bits, then one big memory-bound prune
// pass (one thread per float4, dropped rows skip the fea read entirely).

#define BATCHES 8

__device__ __forceinline__ unsigned f2key(float x) {
    unsigned u = __float_as_uint(x);
    return (u & 0x80000000u) ? ~u : (u | 0x80000000u);
}
__device__ __forceinline__ float key2f(unsigned k) {
    unsigned u = (k & 0x80000000u) ? (k & 0x7FFFFFFFu) : ~k;
    return __uint_as_float(u);
}

// Workspace layout (uint32 units)
static constexpr int HIST_OFF   = 0;      // 4 passes x 8 batches x 256 bins
static constexpr int COUNTS_OFF = 8192;   // 8
static constexpr int REMK_OFF   = 8200;   // 8  remaining rank per batch
static constexpr int PREFIX_OFF = 8208;   // 8  accumulated key prefix
static constexpr int ACTIVE_OFF = 8216;   // 8
static constexpr int THRESH_OFF = 8224;   // 8  (float)
static constexpr int WS_INTS    = 8232;

// ---- Pass 0 histogram (all elements, LDS hist) + counts come from bin sums
__global__ __launch_bounds__(256) void hist0_kernel(const float* __restrict__ pred,
                                                    const int* __restrict__ bids,
                                                    unsigned* __restrict__ hist,
                                                    int n) {
    __shared__ unsigned lh[BATCHES * 256];
    for (int i = threadIdx.x; i < BATCHES * 256; i += blockDim.x) lh[i] = 0u;
    __syncthreads();
    int stride = gridDim.x * blockDim.x;
    for (int i = blockIdx.x * blockDim.x + threadIdx.x; i < n; i += stride) {
        int b = bids[i];
        unsigned key = f2key(pred[i]);
        atomicAdd(&lh[b * 256 + (key >> 24)], 1u);
    }
    __syncthreads();
    for (int i = threadIdx.x; i < BATCHES * 256; i += blockDim.x) {
        unsigned v = lh[i];
        if (v) atomicAdd(&hist[i], v);
    }
}

// ---- Pass 0 scan: counts, rank init, first prefix byte
__global__ void scan0_kernel(const unsigned* __restrict__ hist,
                             const int* __restrict__ target,
                             unsigned* __restrict__ counts,
                             unsigned* __restrict__ remk,
                             unsigned* __restrict__ prefix,
                             unsigned* __restrict__ active) {
    int b = threadIdx.x;
    if (b >= BATCHES) return;
    const unsigned* h = hist + b * 256;
    unsigned total = 0;
    for (int i = 0; i < 256; i++) total += h[i];
    counts[b] = total;
    int t = target[b];
    if ((int)total > t && total > 0) {
        unsigned r = total - (unsigned)t - 1u;  // 0-indexed rank, >= 0
        unsigned cum = 0;
        int bin = 255;
        for (int i = 0; i < 256; i++) {
            unsigned c = h[i];
            if (cum + c > r) { bin = i; break; }
            cum += c;
        }
        prefix[b] = (unsigned)bin;
        remk[b] = r - cum;
        active[b] = 1u;
    } else {
        active[b] = 0u;
    }
}

// ---- Passes 1..3 histogram: only prefix-matching elements (few), global atomics
__global__ __launch_bounds__(256) void histN_kernel(const float* __restrict__ pred,
                                                    const int* __restrict__ bids,
                                                    const unsigned* __restrict__ prefix,
                                                    const unsigned* __restrict__ active,
                                                    unsigned* __restrict__ hist,
                                                    int n, int shiftHi, int shiftBin) {
    int i = blockIdx.x * blockDim.x + threadIdx.x;
    if (i >= n) return;
    int b = bids[i];
    if (!active[b]) return;
    unsigned key = f2key(pred[i]);
    if ((key >> shiftHi) == prefix[b])
        atomicAdd(&hist[b * 256 + ((key >> shiftBin) & 0xFFu)], 1u);
}

// ---- Passes 1..3 scan (finalize=1 on last pass writes thresh)
__global__ void scanN_kernel(const unsigned* __restrict__ hist,
                             unsigned* __restrict__ remk,
                             unsigned* __restrict__ prefix,
                             const unsigned* __restrict__ active,
                             float* __restrict__ thresh,
                             int finalize) {
    int b = threadIdx.x;
    if (b >= BATCHES) return;
    if (active[b]) {
        const unsigned* h = hist + b * 256;
        unsigned r = remk[b];
        unsigned cum = 0;
        int bin = 255;
        for (int i = 0; i < 256; i++) {
            unsigned c = h[i];
            if (cum + c > r) { bin = i; break; }
            cum += c;
        }
        prefix[b] = (prefix[b] << 8) | (unsigned)bin;
        remk[b] = r - cum;
        if (finalize) thresh[b] = key2f(prefix[b]);
    } else {
        if (finalize) thresh[b] = -FLT_MAX;
    }
}

// ---- Prune: one thread per float4 (16 threads per row of 64 floats)
__global__ __launch_bounds__(256) void prune_kernel(const float* __restrict__ fea,
                                                    const float* __restrict__ pred,
                                                    const int* __restrict__ bids,
                                                    const float* __restrict__ thresh,
                                                    float* __restrict__ out,
                                                    int n) {
    int idx = blockIdx.x * blockDim.x + threadIdx.x;
    int row = idx >> 4;
    int l = idx & 15;
    if (row >= n) return;
    int b = bids[row];
    bool kp = pred[row] > thresh[b];
    float4* dst = (float4*)out + (size_t)row * 16 + l;
    if (kp) {
        *dst = ((const float4*)fea)[(size_t)row * 16 + l];
    } else {
        *dst = make_float4(0.f, 0.f, 0.f, 0.f);
    }
    if (l == 0) out[(size_t)n * 64 + row] = kp ? 1.0f : 0.0f;
}

extern "C" void kernel_launch(void* const* d_in, const int* in_sizes, int n_in,
                              void* d_out, int out_size, void* d_ws, size_t ws_size,
                              hipStream_t stream) {
    const float* fea    = (const float*)d_in[0];
    const float* pred   = (const float*)d_in[1];
    const int*   bids   = (const int*)d_in[2];
    const int*   target = (const int*)d_in[3];
    float* out = (float*)d_out;
    int n = in_sizes[1];  // pred_f element count = N

    unsigned* ws      = (unsigned*)d_ws;
    unsigned* hist    = ws + HIST_OFF;    // [4][8][256]
    unsigned* counts  = ws + COUNTS_OFF;
    unsigned* remk    = ws + REMK_OFF;
    unsigned* prefix  = ws + PREFIX_OFF;
    unsigned* active  = ws + ACTIVE_OFF;
    float*    thresh  = (float*)(ws + THRESH_OFF);

    hipMemsetAsync(d_ws, 0, WS_INTS * sizeof(unsigned), stream);

    // Pass 0
    hist0_kernel<<<1024, 256, 0, stream>>>(pred, bids, hist, n);
    scan0_kernel<<<1, 64, 0, stream>>>(hist, target, counts, remk, prefix, active);

    // Passes 1..3
    int nblk = (n + 255) / 256;
    for (int p = 1; p <= 3; p++) {
        unsigned* hp = hist + p * BATCHES * 256;
        int shiftHi = 32 - 8 * p;   // 24, 16, 8
        int shiftBin = 24 - 8 * p;  // 16, 8, 0
        histN_kernel<<<nblk, 256, 0, stream>>>(pred, bids, prefix, active, hp, n,
                                               shiftHi, shiftBin);
        scanN_kernel<<<1, 64, 0, stream>>>(hp, remk, prefix, active, thresh,
                                           p == 3 ? 1 : 0);
    }

    // Prune + keep output
    long total4 = (long)n * 16;
    int pblk = (int)((total4 + 255) / 256);
    prune_kernel<<<pblk, 256, 0, stream>>>(fea, pred, bids, thresh, out, n);
}